// Round 19
// baseline (812.754 us; speedup 1.0000x reference)
//
#include <hip/hip_runtime.h>
#include <hip/hip_bf16.h>

typedef unsigned short u16;
typedef __attribute__((ext_vector_type(8))) short bf16x8;
typedef __attribute__((ext_vector_type(8))) unsigned short u16x8;
typedef __attribute__((ext_vector_type(4))) unsigned short u16x4;
typedef __attribute__((ext_vector_type(4))) float f32x4;

__device__ inline float b2f(u16 u) {
    union { unsigned u32; float f; } x; x.u32 = ((unsigned)u) << 16; return x.f;
}
__device__ inline u16 f2b(float f) {
    return __builtin_bit_cast(u16, __float2bfloat16(f));
}

// tanh-form GELU via exp2 (log2e folded): v * sigmoid(u), u = v*(c1 + c3 v^2)
__device__ inline float fast_gelu(float v) {
    float u = v * (2.302282f + 0.1029404f * v * v);   // constants pre-scaled by log2e
    return v * __builtin_amdgcn_rcpf(1.0f + __builtin_amdgcn_exp2f(-u));
}

#define GLOAD_LDS16(g, l) \
    __builtin_amdgcn_global_load_lds((const __attribute__((address_space(1))) void*)(const void*)(g), \
                                     (__attribute__((address_space(3))) void*)(void*)(l), 16, 0, 0)
#define FENCE() asm volatile("" ::: "memory")

// ---------------- LN1 + shift + window partition -> bf16 ----------------
template<int INBF16>
__global__ __launch_bounds__(256)
void ln_win_kernel(const void* __restrict__ xin, const float* __restrict__ g,
                   const float* __restrict__ b, u16* __restrict__ xw, int shift)
{
    int wid = blockIdx.x * 4 + (threadIdx.x >> 6);
    int lane = threadIdx.x & 63;
    int win = wid >> 6, tok = wid & 63;
    int bb = win >> 6, wib = win & 63;
    int h = (((wib >> 3) << 3) + (tok >> 3) + shift) & 63;
    int w = (((wib & 7) << 3) + (tok & 7) + shift) & 63;
    size_t src = ((size_t)bb * 4096 + h * 64 + w) * 256;
    float v0, v1, v2, v3;
    int c = lane * 4;
    if (INBF16) {
        u16x4 v = ((const u16x4*)((const u16*)xin + src))[lane];
        v0 = b2f(v[0]); v1 = b2f(v[1]); v2 = b2f(v[2]); v3 = b2f(v[3]);
    } else {
        float4 v = ((const float4*)((const float*)xin + src))[lane];
        v0 = v.x; v1 = v.y; v2 = v.z; v3 = v.w;
    }
    float s = v0 + v1 + v2 + v3;
    float s2 = v0*v0 + v1*v1 + v2*v2 + v3*v3;
    for (int k = 32; k > 0; k >>= 1) { s += __shfl_xor(s, k); s2 += __shfl_xor(s2, k); }
    float mean = s * (1.f/256.f);
    float var  = s2 * (1.f/256.f) - mean*mean;
    float rs = rsqrtf(var + 1e-5f);
    u16x4 o;
    o[0] = f2b((v0 - mean) * rs * g[c+0] + b[c+0]);
    o[1] = f2b((v1 - mean) * rs * g[c+1] + b[c+1]);
    o[2] = f2b((v2 - mean) * rs * g[c+2] + b[c+2]);
    o[3] = f2b((v3 - mean) * rs * g[c+3] + b[c+3]);
    *(u16x4*)(xw + (size_t)wid * 256 + c) = o;
}

// ---------------- weight transpose f32[K][N] -> bf16 Wt[N][K] --------------
__global__ __launch_bounds__(256)
void transpose_w(const float* __restrict__ W, u16* __restrict__ Wt, int K, int N)
{
    __shared__ float t[32][33];
    int nb = blockIdx.x * 32, kb = blockIdx.y * 32;
    int tx = threadIdx.x & 31, ty = threadIdx.x >> 5;
    #pragma unroll
    for (int r = 0; r < 32; r += 8)
        t[ty + r][tx] = W[(size_t)(kb + ty + r) * N + nb + tx];
    __syncthreads();
    #pragma unroll
    for (int r = 0; r < 32; r += 8)
        Wt[(size_t)(nb + ty + r) * K + kb + tx] = f2b(t[tx][ty + r]);
}

// ---------------- bias(+mask) table: bmT[cls][h][k][q] * log2e -------------
__global__ __launch_bounds__(256)
void build_bias(const float* __restrict__ rpb, float* __restrict__ bmT)
{
    int idx = blockIdx.x * 256 + threadIdx.x;      // 4*8*64*64 = 131072
    int q = idx & 63, k = (idx >> 6) & 63, h = (idx >> 12) & 7, cls = idx >> 15;
    int qh = q >> 3, qw = q & 7, kh = k >> 3, kw = k & 7;
    float v = rpb[((qh - kh + 7) * 15 + (qw - kw + 7)) * 8 + h];
    int ch = cls >> 1, cw = cls & 1;
    int rq = (ch ? (qh < 4 ? 1 : 2) : 0) * 3 + (cw ? (qw < 4 ? 1 : 2) : 0);
    int rk = (ch ? (kh < 4 ? 1 : 2) : 0) * 3 + (cw ? (kw < 4 ? 1 : 2) : 0);
    if (rq != rk) v -= 100.f;
    bmT[idx] = v * 1.4426950408889634f;
}

// ======== A-stationary GEMM (K=256): A in VGPRs, B streamed via LDS ========
// 4 waves x 32 rows = 128 rows/block; grid 512 -> 2 blocks/CU.
// ALN=1 (MLP1): A rows are raw bf16 of x1b; LN2(1e-5) o LN3(1e-6) fused into
// the A-load using packed fragments + algebraic second-LN stats (r10 math,
// now spill-free because input is bf16: af IS the row data, 32 VGPR).
// Epilogue before the trailing barrier (r18). Counted-vmcnt ladder unchanged.
// EPI 0: bf16+bias (QKV); EPI 1: gelu->bf16 (MLP1);
// EPI 2: bf16 winrev + residual (resid f32 if RBF16=0, bf16 if RBF16=1).
template<int EPI, int RBF16, int ALN>
__global__ __launch_bounds__(256, 2)
void areg_gemm(const u16* __restrict__ A, const u16* __restrict__ Bt,
               const float* __restrict__ bias, void* __restrict__ out,
               const void* __restrict__ resid,
               const float* __restrict__ lg1, const float* __restrict__ lb1,
               const float* __restrict__ lg2, const float* __restrict__ lb2,
               int N, int shift)
{
    constexpr int K = 256;
    __shared__ u16 Bs[2][8][64][32];   // 64 KB
    __shared__ float lnp[4][256];      // 4 KB (ALN only)
    const int tid = threadIdx.x, lane = tid & 63, wv = tid >> 6;
    const int g = lane >> 4, r = lane & 15;
    const int bid = blockIdx.x;
    const int bm = (bid & 7) * 64 + (bid >> 3);    // XCD-chunked, 512 = 8*64
    const int row0 = bm * 128 + wv * 32;

    if (ALN) {
        if (tid < 256) {
            lnp[0][tid] = lg1[tid]; lnp[1][tid] = lb1[tid];
            lnp[2][tid] = lg2[tid]; lnp[3][tid] = lb2[tid];
        }
    }

    const int NB = N >> 6;
#define STAGE(bn_, buf_) do { \
        _Pragma("unroll") \
        for (int it = 0; it < 8; ++it) { \
            const int S = it * 256 + wv * 64 + lane; \
            const int ks_ = S >> 8, col_ = (S >> 2) & 63; \
            const int k8_ = (S & 3) ^ (col_ & 3) ^ ((col_ >> 2) & 1); \
            GLOAD_LDS16(Bt + (size_t)((bn_) * 64 + col_) * K + ks_ * 32 + k8_ * 8, \
                        &Bs[buf_][0][0][0] + (size_t)(it * 256 + wv * 64) * 8); \
        } \
    } while (0)

    FENCE();
    STAGE(0, 0);
    if (ALN) __syncthreads();   // lnp visible; also drains STAGE(0) (harmless)

    // ---- A fragments
    bf16x8 af[2][8];
    #pragma unroll
    for (int rf = 0; rf < 2; ++rf)
        #pragma unroll
        for (int ks = 0; ks < 8; ++ks)
            af[rf][ks] = *(const bf16x8*)(A + (size_t)(row0 + rf * 16 + r) * K + ks * 32 + g * 8);

    if (ALN) {
        // channel constants (row-independent), this thread's 64 channels + g-reduce
        float cg = 0.f, cg2 = 0.f, cb = 0.f, cb2 = 0.f, cgb = 0.f;
        #pragma unroll
        for (int ks = 0; ks < 8; ++ks)
            #pragma unroll
            for (int e = 0; e < 8; ++e) {
                const int c = ks * 32 + g * 8 + e;
                const float gv = lnp[0][c], bv = lnp[1][c];
                cg += gv; cg2 += gv * gv; cb += bv; cb2 += bv * bv; cgb += gv * bv;
            }
        cg  += __shfl_xor(cg, 16);  cg  += __shfl_xor(cg, 32);
        cg2 += __shfl_xor(cg2, 16); cg2 += __shfl_xor(cg2, 32);
        cb  += __shfl_xor(cb, 16);  cb  += __shfl_xor(cb, 32);
        cb2 += __shfl_xor(cb2, 16); cb2 += __shfl_xor(cb2, 32);
        cgb += __shfl_xor(cgb, 16); cgb += __shfl_xor(cgb, 32);
        #pragma unroll
        for (int rf = 0; rf < 2; ++rf) {
            float s = 0.f, s2 = 0.f, sg = 0.f, sg2x = 0.f, sg2x2 = 0.f, sgbx = 0.f;
            #pragma unroll
            for (int ks = 0; ks < 8; ++ks) {
                const u16x8 xp = __builtin_bit_cast(u16x8, af[rf][ks]);
                #pragma unroll
                for (int e = 0; e < 8; ++e) {
                    const int c = ks * 32 + g * 8 + e;
                    const float xv = b2f(xp[e]);
                    const float gv = lnp[0][c], bv = lnp[1][c];
                    s += xv; s2 += xv * xv;
                    sg += gv * xv; sg2x += gv * gv * xv;
                    sg2x2 += gv * gv * xv * xv; sgbx += gv * bv * xv;
                }
            }
            s     += __shfl_xor(s, 16);     s     += __shfl_xor(s, 32);
            s2    += __shfl_xor(s2, 16);    s2    += __shfl_xor(s2, 32);
            sg    += __shfl_xor(sg, 16);    sg    += __shfl_xor(sg, 32);
            sg2x  += __shfl_xor(sg2x, 16);  sg2x  += __shfl_xor(sg2x, 32);
            sg2x2 += __shfl_xor(sg2x2, 16); sg2x2 += __shfl_xor(sg2x2, 32);
            sgbx  += __shfl_xor(sgbx, 16);  sgbx  += __shfl_xor(sgbx, 32);
            const float m1 = s * (1.f / 256.f);
            const float rs1 = rsqrtf(s2 * (1.f / 256.f) - m1 * m1 + 1e-5f);
            const float sumy  = rs1 * (sg - m1 * cg) + cb;
            const float sumy2 = rs1 * rs1 * (sg2x2 - 2.f * m1 * sg2x + m1 * m1 * cg2)
                              + 2.f * rs1 * (sgbx - m1 * cgb) + cb2;
            const float m2 = sumy * (1.f / 256.f);
            const float rs2 = rsqrtf(sumy2 * (1.f / 256.f) - m2 * m2 + 1e-6f);
            #pragma unroll
            for (int ks = 0; ks < 8; ++ks) {
                const u16x8 xp = __builtin_bit_cast(u16x8, af[rf][ks]);
                u16x8 op;
                #pragma unroll
                for (int e = 0; e < 8; ++e) {
                    const int c = ks * 32 + g * 8 + e;
                    const float y = (b2f(xp[e]) - m1) * rs1 * lnp[0][c] + lnp[1][c];
                    op[e] = f2b((y - m2) * rs2 * lnp[2][c] + lnp[3][c]);
                }
                af[rf][ks] = __builtin_bit_cast(bf16x8, op);
            }
        }
    }

    const int rc = (g ^ (r & 3) ^ ((r >> 2) & 1)) * 8;   // swizzled read slot

    for (int bn = 0; bn < NB; ++bn) {
        const int cur = bn & 1;
        if (bn + 1 < NB) { STAGE(bn + 1, cur ^ 1); }
        if (bn == 0) {
            asm volatile("s_waitcnt vmcnt(8)" ::: "memory");
        } else if (bn + 1 < NB) {
            if (EPI == 2) asm volatile("s_waitcnt vmcnt(24)" ::: "memory");
            else          asm volatile("s_waitcnt vmcnt(16)" ::: "memory");
        } else {
            if (EPI == 2) asm volatile("s_waitcnt vmcnt(16)" ::: "memory");
            else          asm volatile("s_waitcnt vmcnt(8)" ::: "memory");
        }
        __builtin_amdgcn_s_barrier();
        FENCE();
        f32x4 acc[4][2] = {};
        #pragma unroll
        for (int ks = 0; ks < 8; ++ks) {
            bf16x8 bf[4];
            #pragma unroll
            for (int cf = 0; cf < 4; ++cf)
                bf[cf] = *(const bf16x8*)(&Bs[cur][ks][cf * 16 + r][rc]);
            __builtin_amdgcn_s_setprio(1);
            #pragma unroll
            for (int cf = 0; cf < 4; ++cf)
                #pragma unroll
                for (int rf = 0; rf < 2; ++rf)
                    acc[cf][rf] = __builtin_amdgcn_mfma_f32_16x16x32_bf16(bf[cf], af[rf][ks], acc[cf][rf], 0, 0, 0);
            __builtin_amdgcn_s_setprio(0);
        }
        asm volatile("s_waitcnt lgkmcnt(0)" ::: "memory");
        __builtin_amdgcn_sched_barrier(0);
        // ---- epilogue BEFORE the barrier (r18): registers/global only
        #pragma unroll
        for (int rf = 0; rf < 2; ++rf) {
            const int row = row0 + rf * 16 + r;
            size_t orow;
            if (EPI == 2) {
                int win = row >> 6, tok = row & 63;
                int bb = win >> 6, wib = win & 63;
                int h = (((wib >> 3) << 3) + (tok >> 3) + shift) & 63;
                int w = (((wib & 7) << 3) + (tok & 7) + shift) & 63;
                orow = (size_t)bb * 4096 + h * 64 + w;
            } else {
                orow = (size_t)row;
            }
            #pragma unroll
            for (int cf = 0; cf < 4; ++cf) {
                const int colb = bn * 64 + cf * 16 + g * 4;
                const f32x4 bv = *(const f32x4*)(bias + colb);
                if (EPI == 0) {
                    u16x4 o;
                    #pragma unroll
                    for (int e = 0; e < 4; ++e) o[e] = f2b(acc[cf][rf][e] + bv[e]);
                    *(u16x4*)((u16*)out + (size_t)row * N + colb) = o;
                } else if (EPI == 1) {
                    u16x4 o;
                    #pragma unroll
                    for (int e = 0; e < 4; ++e) o[e] = f2b(fast_gelu(acc[cf][rf][e] + bv[e]));
                    *(u16x4*)((u16*)out + (size_t)row * N + colb) = o;
                } else {
                    float rv[4];
                    if (RBF16) {
                        const u16x4 rb = *(const u16x4*)((const u16*)resid + orow * N + colb);
                        #pragma unroll
                        for (int e = 0; e < 4; ++e) rv[e] = b2f(rb[e]);
                    } else {
                        const f32x4 rb = *(const f32x4*)((const float*)resid + orow * N + colb);
                        #pragma unroll
                        for (int e = 0; e < 4; ++e) rv[e] = rb[e];
                    }
                    u16x4 o;
                    #pragma unroll
                    for (int e = 0; e < 4; ++e) o[e] = f2b(rv[e] + acc[cf][rf][e] + bv[e]);
                    *(u16x4*)((u16*)out + orow * N + colb) = o;
                }
            }
        }
        FENCE();
        __builtin_amdgcn_s_barrier();
        FENCE();
    }
#undef STAGE
}

// ======== general-K 128x128 GEMM (MLP2): 4-buf, depth-2, 1 barrier/iter ====
template<int OUTBF16>
__global__ __launch_bounds__(256)
void gemm_k4(const u16* __restrict__ A, const u16* __restrict__ Bt,
             const float* __restrict__ bias, void* __restrict__ out,
             const u16* __restrict__ resid, int M, int N, int K)
{
    __shared__ u16 As[4][128][32];
    __shared__ u16 Bs[4][128][32];
    const int tid = threadIdx.x, lane = tid & 63, wv = tid >> 6;
    const int g = lane >> 4, r = lane & 15;
    const int wr = wv >> 1, wc = wv & 1;
    const int nwg = gridDim.x * gridDim.y;
    const int lid = blockIdx.y * gridDim.x + blockIdx.x;
    const int qq = nwg >> 3, r8 = nwg & 7;
    const int xcd = lid & 7, pos = lid >> 3;
    const int nid = (xcd < r8 ? xcd * (qq + 1) : r8 * (qq + 1) + (xcd - r8) * qq) + pos;
    const int bm = nid / gridDim.x, bn = nid % gridDim.x;
    f32x4 acc[4][4] = {};
    const int arow = wv * 16 + (lane >> 2);
    const int scol = (((lane & 3) ^ ((lane >> 2) & 3) ^ ((lane >> 4) & 1)) * 8);
    const u16* gA = A + (size_t)(bm * 128 + arow) * K + scol;
    const u16* gB = Bt + (size_t)(bn * 128 + arow) * K + scol;
    const int nk = K >> 5;
    const int rc = (g ^ (r & 3) ^ ((r >> 2) & 1)) * 8;

#define STAGE(t) do { \
        u16* a_ = &As[(t) & 3][0][0]; u16* b_ = &Bs[(t) & 3][0][0]; \
        GLOAD_LDS16(gA + (size_t)(t) * 32,                    a_ + wv * 512); \
        GLOAD_LDS16(gA + (size_t)(t) * 32 + (size_t)64 * K,   a_ + 2048 + wv * 512); \
        GLOAD_LDS16(gB + (size_t)(t) * 32,                    b_ + wv * 512); \
        GLOAD_LDS16(gB + (size_t)(t) * 32 + (size_t)64 * K,   b_ + 2048 + wv * 512); \
    } while (0)

    STAGE(0);
    STAGE(1);
    for (int kt = 0; kt < nk; ++kt) {
        const int cur = kt & 3;
        if (kt + 2 < nk) {
            STAGE(kt + 2);
            asm volatile("s_waitcnt vmcnt(8)" ::: "memory");
        } else if (kt + 1 < nk) {
            asm volatile("s_waitcnt vmcnt(4)" ::: "memory");
        } else {
            asm volatile("s_waitcnt vmcnt(0)" ::: "memory");
        }
        __builtin_amdgcn_s_barrier();
        FENCE();
        bf16x8 af[4], bf[4];
        #pragma unroll
        for (int i = 0; i < 4; ++i)
            af[i] = *(const bf16x8*)(&As[cur][wr * 64 + i * 16 + r][rc]);
        #pragma unroll
        for (int j = 0; j < 4; ++j)
            bf[j] = *(const bf16x8*)(&Bs[cur][wc * 64 + j * 16 + r][rc]);
        __builtin_amdgcn_s_setprio(1);
        #pragma unroll
        for (int j = 0; j < 4; ++j)
            #pragma unroll
            for (int i = 0; i < 4; ++i)
                acc[j][i] = __builtin_amdgcn_mfma_f32_16x16x32_bf16(bf[j], af[i], acc[j][i], 0, 0, 0);
        __builtin_amdgcn_s_setprio(0);
        asm volatile("s_waitcnt lgkmcnt(0)" ::: "memory");
        __builtin_amdgcn_sched_barrier(0);
    }
#undef STAGE

    #pragma unroll
    for (int i = 0; i < 4; ++i) {
        const int row = bm * 128 + wr * 64 + i * 16 + r;
        #pragma unroll
        for (int j = 0; j < 4; ++j) {
            const int colb = bn * 128 + wc * 64 + j * 16 + g * 4;
            const f32x4 bv = *(const f32x4*)(bias + colb);
            const u16x4 rb = *(const u16x4*)(resid + (size_t)row * N + colb);
            if (OUTBF16) {
                u16x4 o;
                #pragma unroll
                for (int e = 0; e < 4; ++e) o[e] = f2b(b2f(rb[e]) + acc[j][i][e] + bv[e]);
                *(u16x4*)((u16*)out + (size_t)row * N + colb) = o;
            } else {
                f32x4 o;
                #pragma unroll
                for (int e = 0; e < 4; ++e) o[e] = b2f(rb[e]) + acc[j][i][e] + bv[e];
                *(f32x4*)((float*)out + (size_t)row * N + colb) = o;
            }
        }
    }
}

// ---------------- MFMA attention: one block per window, wave = 2 heads -----
template<int SHIFTED>
__global__ __launch_bounds__(256)
void attn_mfma(const u16* __restrict__ qkv, const float* __restrict__ bmT,
               u16* __restrict__ out)
{
    __shared__ u16 pbuf[4][64 * 72];
    __shared__ u16 vbuf[4][32 * 72];
    const int tid = threadIdx.x, lane = tid & 63, wv = tid >> 6;
    const int g = lane >> 4, r = lane & 15;
    const int win = blockIdx.x;
    u16* P  = pbuf[wv];
    u16* Vt = vbuf[wv];
    const u16* base = qkv + (size_t)win * 64 * 768;
    int cls = 0;
    if (SHIFTED) {
        int wib = win & 63;
        cls = (((wib >> 3) == 7) ? 2 : 0) + (((wib & 7) == 7) ? 1 : 0);
    }
    const float sc = 0.17677669529663687f * 1.4426950408889634f;

    for (int hh = 0; hh < 2; ++hh) {
        const int h = wv * 2 + hh;
        const float* bmh = bmT + ((size_t)cls * 8 + h) * 4096;
        bf16x8 kf[4], qf[4];
        #pragma unroll
        for (int i = 0; i < 4; ++i) {
            kf[i] = *(const bf16x8*)(base + (size_t)(i * 16 + r) * 768 + 256 + h * 32 + g * 8);
            qf[i] = *(const bf16x8*)(base + (size_t)(i * 16 + r) * 768 +       h * 32 + g * 8);
        }
        #pragma unroll
        for (int d0 = 0; d0 < 32; d0 += 8) {
            u16x8 vv = *(const u16x8*)(base + (size_t)lane * 768 + 512 + h * 32 + d0);
            #pragma unroll
            for (int e = 0; e < 8; ++e) Vt[(d0 + e) * 72 + lane] = vv[e];
        }
        f32x4 acc[4][4] = {};
        #pragma unroll
        for (int i = 0; i < 4; ++i)
            #pragma unroll
            for (int j = 0; j < 4; ++j)
                acc[i][j] = __builtin_amdgcn_mfma_f32_16x16x32_bf16(kf[i], qf[j], acc[i][j], 0, 0, 0);
        #pragma unroll
        for (int i = 0; i < 4; ++i) {
            const int kb = (i * 16 + g * 4) * 64;
            #pragma unroll
            for (int j = 0; j < 4; ++j) {
                const int qq = j * 16 + r;
                #pragma unroll
                for (int rr = 0; rr < 4; ++rr)
                    acc[i][j][rr] = acc[i][j][rr] * sc + bmh[kb + rr * 64 + qq];
            }
        }
        float inv_[4];
        #pragma unroll
        for (int j = 0; j < 4; ++j) {
            float m = acc[0][j][0];
            #pragma unroll
            for (int i = 0; i < 4; ++i)
                #pragma unroll
                for (int rr = 0; rr < 4; ++rr) m = fmaxf(m, acc[i][j][rr]);
            m = fmaxf(m, __shfl_xor(m, 16));
            m = fmaxf(m, __shfl_xor(m, 32));
            float s = 0.f;
            #pragma unroll
            for (int i = 0; i < 4; ++i)
                #pragma unroll
                for (int rr = 0; rr < 4; ++rr) {
                    float p = exp2f(acc[i][j][rr] - m);
                    acc[i][j][rr] = p; s += p;
                }
            s += __shfl_xor(s, 16);
            s += __shfl_xor(s, 32);
            inv_[j] = 1.f / s;
        }
        #pragma unroll
        for (int j = 0; j < 4; ++j) {
            const float iv = inv_[j];
            #pragma unroll
            for (int i = 0; i < 4; ++i) {
                u16x4 w;
                #pragma unroll
                for (int rr = 0; rr < 4; ++rr) w[rr] = f2b(acc[i][j][rr] * iv);
                *(u16x4*)(P + (j * 16 + r) * 72 + i * 16 + g * 4) = w;
            }
        }
        f32x4 o[2][4] = {};
        #pragma unroll
        for (int ks = 0; ks < 2; ++ks) {
            bf16x8 pa[4], vb[2];
            #pragma unroll
            for (int i = 0; i < 4; ++i)
                pa[i] = *(const bf16x8*)(P + (i * 16 + r) * 72 + ks * 32 + g * 8);
            #pragma unroll
            for (int j = 0; j < 2; ++j)
                vb[j] = *(const bf16x8*)(Vt + (j * 16 + r) * 72 + ks * 32 + g * 8);
            #pragma unroll
            for (int j = 0; j < 2; ++j)
                #pragma unroll
                for (int i = 0; i < 4; ++i)
                    o[j][i] = __builtin_amdgcn_mfma_f32_16x16x32_bf16(vb[j], pa[i], o[j][i], 0, 0, 0);
        }
        u16* op = out + (size_t)win * 64 * 256 + h * 32;
        #pragma unroll
        for (int i = 0; i < 4; ++i) {
            const int qrow = i * 16 + r;
            #pragma unroll
            for (int j = 0; j < 2; ++j) {
                u16x4 w;
                #pragma unroll
                for (int rr = 0; rr < 4; ++rr) w[rr] = f2b(o[j][i][rr]);
                *(u16x4*)(op + (size_t)qrow * 256 + j * 16 + g * 4) = w;
            }
        }
    }
}

// ---------------------------------------------------------------------------
extern "C" void kernel_launch(void* const* d_in, const int* in_sizes, int n_in,
                              void* d_out, int out_size, void* d_ws, size_t ws_size,
                              hipStream_t stream)
{
    (void)in_sizes; (void)n_in; (void)out_size; (void)ws_size;
    const float* x = (const float*)d_in[0];
    char* ws = (char*)d_ws;
    size_t off = 0;
    auto alloc = [&](size_t bytes) { void* p = ws + off; off += (bytes + 255) & ~(size_t)255; return p; };

    u16 *wtq[2], *wto[2], *wt1[2], *wt2[2];
    float* bmT[2];
    for (int i = 0; i < 2; ++i) {
        wtq[i] = (u16*)alloc((size_t)768 * 256 * 2);
        wto[i] = (u16*)alloc((size_t)256 * 256 * 2);
        wt1[i] = (u16*)alloc((size_t)1024 * 256 * 2);
        wt2[i] = (u16*)alloc((size_t)256 * 1024 * 2);
        bmT[i] = (float*)alloc((size_t)4 * 8 * 64 * 64 * 4);
    }
    u16*  xw  = (u16*)alloc((size_t)65536 * 256 * 2);    // LN out / attn out
    u16*  big = (u16*)alloc((size_t)65536 * 1024 * 2);   // qkv / mlp hidden
    u16*  x1b = (u16*)alloc((size_t)65536 * 256 * 2);    // residual stream (bf16)
    u16*  xob = (u16*)alloc((size_t)65536 * 256 * 2);    // block0 output (bf16)
    float* outp = (float*)d_out;

    for (int blk = 0; blk < 2; ++blk) {
        const float* const* P = (const float* const*)(d_in + 1 + blk * 15);
        transpose_w<<<dim3(768 / 32, 256 / 32), 256, 0, stream>>>(P[2], wtq[blk], 256, 768);
        transpose_w<<<dim3(256 / 32, 256 / 32), 256, 0, stream>>>(P[5], wto[blk], 256, 256);
        transpose_w<<<dim3(1024 / 32, 256 / 32), 256, 0, stream>>>(P[11], wt1[blk], 256, 1024);
        transpose_w<<<dim3(256 / 32, 1024 / 32), 256, 0, stream>>>(P[13], wt2[blk], 1024, 256);
        build_bias<<<512, 256, 0, stream>>>(P[4], bmT[blk]);
    }

    // ---- block 0 (resid source: x f32; block output -> xob bf16)
    {
        const float* const* P = (const float* const*)(d_in + 1);
        ln_win_kernel<0><<<16384, 256, 0, stream>>>(x, P[0], P[1], xw, 0);
        areg_gemm<0, 0, 0><<<512, 256, 0, stream>>>(xw, wtq[0], P[3], big, nullptr,
                                                    nullptr, nullptr, nullptr, nullptr, 768, 0);
        attn_mfma<0><<<1024, 256, 0, stream>>>(big, bmT[0], xw);
        areg_gemm<2, 0, 0><<<512, 256, 0, stream>>>(xw, wto[0], P[6], x1b, x,
                                                    nullptr, nullptr, nullptr, nullptr, 256, 0);
        // MLP1 with fused LN2 o LN3 in the A-load
        areg_gemm<1, 0, 1><<<512, 256, 0, stream>>>(x1b, wt1[0], P[12], big, nullptr,
                                                    P[7], P[8], P[9], P[10], 1024, 0);
        gemm_k4<1><<<dim3(2, 512), 256, 0, stream>>>(big, wt2[0], P[14], xob, x1b, 65536, 256, 1024);
    }
    // ---- block 1 (resid source: xob bf16; final output -> d_out f32)
    {
        const float* const* P = (const float* const*)(d_in + 1 + 15);
        ln_win_kernel<1><<<16384, 256, 0, stream>>>(xob, P[0], P[1], xw, 4);
        areg_gemm<0, 0, 0><<<512, 256, 0, stream>>>(xw, wtq[1], P[3], big, nullptr,
                                                    nullptr, nullptr, nullptr, nullptr, 768, 0);
        attn_mfma<1><<<1024, 256, 0, stream>>>(big, bmT[1], xw);
        areg_gemm<2, 1, 0><<<512, 256, 0, stream>>>(xw, wto[1], P[6], x1b, xob,
                                                    nullptr, nullptr, nullptr, nullptr, 256, 4);
        areg_gemm<1, 0, 1><<<512, 256, 0, stream>>>(x1b, wt1[1], P[12], big, nullptr,
                                                    P[7], P[8], P[9], P[10], 1024, 0);
        gemm_k4<0><<<dim3(2, 512), 256, 0, stream>>>(big, wt2[1], P[14], outp, x1b, 65536, 256, 1024);
    }
}

// Round 20
// 622.938 us; speedup vs baseline: 1.3047x; 1.3047x over previous
//
#include <hip/hip_runtime.h>
#include <hip/hip_bf16.h>

typedef unsigned short u16;
typedef __attribute__((ext_vector_type(8))) short bf16x8;
typedef __attribute__((ext_vector_type(8))) unsigned short u16x8;
typedef __attribute__((ext_vector_type(4))) unsigned short u16x4;
typedef __attribute__((ext_vector_type(4))) float f32x4;

__device__ inline float b2f(u16 u) {
    union { unsigned u32; float f; } x; x.u32 = ((unsigned)u) << 16; return x.f;
}
__device__ inline u16 f2b(float f) {
    return __builtin_bit_cast(u16, __float2bfloat16(f));
}

// tanh-form GELU via exp2 (log2e folded): v * sigmoid(u), u = v*(c1 + c3 v^2)
__device__ inline float fast_gelu(float v) {
    float u = v * (2.302282f + 0.1029404f * v * v);   // constants pre-scaled by log2e
    return v * __builtin_amdgcn_rcpf(1.0f + __builtin_amdgcn_exp2f(-u));
}

#define GLOAD_LDS16(g, l) \
    __builtin_amdgcn_global_load_lds((const __attribute__((address_space(1))) void*)(const void*)(g), \
                                     (__attribute__((address_space(3))) void*)(void*)(l), 16, 0, 0)
#define FENCE() asm volatile("" ::: "memory")

// ---------------- LN1 + shift + window partition -> bf16 ----------------
template<int INBF16>
__global__ __launch_bounds__(256)
void ln_win_kernel(const void* __restrict__ xin, const float* __restrict__ g,
                   const float* __restrict__ b, u16* __restrict__ xw, int shift)
{
    int wid = blockIdx.x * 4 + (threadIdx.x >> 6);
    int lane = threadIdx.x & 63;
    int win = wid >> 6, tok = wid & 63;
    int bb = win >> 6, wib = win & 63;
    int h = (((wib >> 3) << 3) + (tok >> 3) + shift) & 63;
    int w = (((wib & 7) << 3) + (tok & 7) + shift) & 63;
    size_t src = ((size_t)bb * 4096 + h * 64 + w) * 256;
    float v0, v1, v2, v3;
    int c = lane * 4;
    if (INBF16) {
        u16x4 v = ((const u16x4*)((const u16*)xin + src))[lane];
        v0 = b2f(v[0]); v1 = b2f(v[1]); v2 = b2f(v[2]); v3 = b2f(v[3]);
    } else {
        float4 v = ((const float4*)((const float*)xin + src))[lane];
        v0 = v.x; v1 = v.y; v2 = v.z; v3 = v.w;
    }
    float s = v0 + v1 + v2 + v3;
    float s2 = v0*v0 + v1*v1 + v2*v2 + v3*v3;
    for (int k = 32; k > 0; k >>= 1) { s += __shfl_xor(s, k); s2 += __shfl_xor(s2, k); }
    float mean = s * (1.f/256.f);
    float var  = s2 * (1.f/256.f) - mean*mean;
    float rs = rsqrtf(var + 1e-5f);
    u16x4 o;
    o[0] = f2b((v0 - mean) * rs * g[c+0] + b[c+0]);
    o[1] = f2b((v1 - mean) * rs * g[c+1] + b[c+1]);
    o[2] = f2b((v2 - mean) * rs * g[c+2] + b[c+2]);
    o[3] = f2b((v3 - mean) * rs * g[c+3] + b[c+3]);
    *(u16x4*)(xw + (size_t)wid * 256 + c) = o;
}

// ---------------- fused LN2(1e-5) then LN3(1e-6), bf16 in -> bf16 ----------
__global__ __launch_bounds__(256)
void ln2_kernel(const u16* __restrict__ xin,
                const float* __restrict__ g1, const float* __restrict__ b1,
                const float* __restrict__ g2, const float* __restrict__ b2,
                u16* __restrict__ out)
{
    int wid = blockIdx.x * 4 + (threadIdx.x >> 6);
    int lane = threadIdx.x & 63;
    u16x4 v = ((const u16x4*)(xin + (size_t)wid * 256))[lane];
    float v0 = b2f(v[0]), v1 = b2f(v[1]), v2 = b2f(v[2]), v3 = b2f(v[3]);
    float s = v0 + v1 + v2 + v3;
    float s2 = v0*v0 + v1*v1 + v2*v2 + v3*v3;
    for (int k = 32; k > 0; k >>= 1) { s += __shfl_xor(s, k); s2 += __shfl_xor(s2, k); }
    float mean = s * (1.f/256.f);
    float var  = s2 * (1.f/256.f) - mean*mean;
    float rs = rsqrtf(var + 1e-5f);
    int c = lane * 4;
    float y0 = (v0 - mean) * rs * g1[c+0] + b1[c+0];
    float y1 = (v1 - mean) * rs * g1[c+1] + b1[c+1];
    float y2 = (v2 - mean) * rs * g1[c+2] + b1[c+2];
    float y3 = (v3 - mean) * rs * g1[c+3] + b1[c+3];
    float t = y0 + y1 + y2 + y3;
    float t2 = y0*y0 + y1*y1 + y2*y2 + y3*y3;
    for (int k = 32; k > 0; k >>= 1) { t += __shfl_xor(t, k); t2 += __shfl_xor(t2, k); }
    float m2 = t * (1.f/256.f);
    float vr = t2 * (1.f/256.f) - m2*m2;
    float rs2 = rsqrtf(vr + 1e-6f);
    u16x4 o;
    o[0] = f2b((y0 - m2) * rs2 * g2[c+0] + b2[c+0]);
    o[1] = f2b((y1 - m2) * rs2 * g2[c+1] + b2[c+1]);
    o[2] = f2b((y2 - m2) * rs2 * g2[c+2] + b2[c+2]);
    o[3] = f2b((y3 - m2) * rs2 * g2[c+3] + b2[c+3]);
    *(u16x4*)(out + (size_t)wid * 256 + c) = o;
}

// ---------------- weight transpose f32[K][N] -> bf16 Wt[N][K] --------------
__global__ __launch_bounds__(256)
void transpose_w(const float* __restrict__ W, u16* __restrict__ Wt, int K, int N)
{
    __shared__ float t[32][33];
    int nb = blockIdx.x * 32, kb = blockIdx.y * 32;
    int tx = threadIdx.x & 31, ty = threadIdx.x >> 5;
    #pragma unroll
    for (int r = 0; r < 32; r += 8)
        t[ty + r][tx] = W[(size_t)(kb + ty + r) * N + nb + tx];
    __syncthreads();
    #pragma unroll
    for (int r = 0; r < 32; r += 8)
        Wt[(size_t)(nb + ty + r) * K + kb + tx] = f2b(t[tx][ty + r]);
}

// ---------------- bias(+mask) table: bmT[cls][h][k][q] * log2e -------------
__global__ __launch_bounds__(256)
void build_bias(const float* __restrict__ rpb, float* __restrict__ bmT)
{
    int idx = blockIdx.x * 256 + threadIdx.x;      // 4*8*64*64 = 131072
    int q = idx & 63, k = (idx >> 6) & 63, h = (idx >> 12) & 7, cls = idx >> 15;
    int qh = q >> 3, qw = q & 7, kh = k >> 3, kw = k & 7;
    float v = rpb[((qh - kh + 7) * 15 + (qw - kw + 7)) * 8 + h];
    int ch = cls >> 1, cw = cls & 1;
    int rq = (ch ? (qh < 4 ? 1 : 2) : 0) * 3 + (cw ? (qw < 4 ? 1 : 2) : 0);
    int rk = (ch ? (kh < 4 ? 1 : 2) : 0) * 3 + (cw ? (kw < 4 ? 1 : 2) : 0);
    if (rq != rk) v -= 100.f;
    bmT[idx] = v * 1.4426950408889634f;
}

// ======== A-stationary GEMM (K=256): A in VGPRs, B streamed via LDS ========
// 4 waves x 32 rows = 128 rows/block; grid 512 -> 2 blocks/CU.
// Epilogue moved BEFORE the trailing barrier (register/global only, no LDS):
// waves drain stores while others are still in MFMA; VMEM issue order and
// the counted-vmcnt ladder are unchanged.
template<int EPI, int RBF16>
__global__ __launch_bounds__(256, 2)
void areg_gemm(const u16* __restrict__ A, const u16* __restrict__ Bt,
               const float* __restrict__ bias, void* __restrict__ out,
               const void* __restrict__ resid, int N, int shift)
{
    constexpr int K = 256;
    __shared__ u16 Bs[2][8][64][32];   // 64 KB
    const int tid = threadIdx.x, lane = tid & 63, wv = tid >> 6;
    const int g = lane >> 4, r = lane & 15;
    const int bid = blockIdx.x;
    const int bm = (bid & 7) * 64 + (bid >> 3);    // XCD-chunked, 512 = 8*64
    const int row0 = bm * 128 + wv * 32;

    bf16x8 af[2][8];
    #pragma unroll
    for (int rf = 0; rf < 2; ++rf)
        #pragma unroll
        for (int ks = 0; ks < 8; ++ks)
            af[rf][ks] = *(const bf16x8*)(A + (size_t)(row0 + rf * 16 + r) * K + ks * 32 + g * 8);

    const int NB = N >> 6;
#define STAGE(bn_, buf_) do { \
        _Pragma("unroll") \
        for (int it = 0; it < 8; ++it) { \
            const int S = it * 256 + wv * 64 + lane; \
            const int ks_ = S >> 8, col_ = (S >> 2) & 63; \
            const int k8_ = (S & 3) ^ (col_ & 3) ^ ((col_ >> 2) & 1); \
            GLOAD_LDS16(Bt + (size_t)((bn_) * 64 + col_) * K + ks_ * 32 + k8_ * 8, \
                        &Bs[buf_][0][0][0] + (size_t)(it * 256 + wv * 64) * 8); \
        } \
    } while (0)

    const int rc = (g ^ (r & 3) ^ ((r >> 2) & 1)) * 8;   // swizzled read slot

    FENCE();
    STAGE(0, 0);
    for (int bn = 0; bn < NB; ++bn) {
        const int cur = bn & 1;
        if (bn + 1 < NB) { STAGE(bn + 1, cur ^ 1); }
        if (bn == 0) {
            asm volatile("s_waitcnt vmcnt(8)" ::: "memory");
        } else if (bn + 1 < NB) {
            if (EPI == 2) asm volatile("s_waitcnt vmcnt(24)" ::: "memory");
            else          asm volatile("s_waitcnt vmcnt(16)" ::: "memory");
        } else {
            if (EPI == 2) asm volatile("s_waitcnt vmcnt(16)" ::: "memory");
            else          asm volatile("s_waitcnt vmcnt(8)" ::: "memory");
        }
        __builtin_amdgcn_s_barrier();
        FENCE();
        f32x4 acc[4][2] = {};
        #pragma unroll
        for (int ks = 0; ks < 8; ++ks) {
            bf16x8 bf[4];
            #pragma unroll
            for (int cf = 0; cf < 4; ++cf)
                bf[cf] = *(const bf16x8*)(&Bs[cur][ks][cf * 16 + r][rc]);
            __builtin_amdgcn_s_setprio(1);
            #pragma unroll
            for (int cf = 0; cf < 4; ++cf)
                #pragma unroll
                for (int rf = 0; rf < 2; ++rf)
                    acc[cf][rf] = __builtin_amdgcn_mfma_f32_16x16x32_bf16(bf[cf], af[rf][ks], acc[cf][rf], 0, 0, 0);
            __builtin_amdgcn_s_setprio(0);
        }
        asm volatile("s_waitcnt lgkmcnt(0)" ::: "memory");
        __builtin_amdgcn_sched_barrier(0);
        // ---- epilogue BEFORE the barrier: registers/global only, overlaps
        //      other waves' MFMA; VMEM order vs STAGE unchanged (ladder exact).
        #pragma unroll
        for (int rf = 0; rf < 2; ++rf) {
            const int row = row0 + rf * 16 + r;
            size_t orow;
            if (EPI == 2) {
                int win = row >> 6, tok = row & 63;
                int bb = win >> 6, wib = win & 63;
                int h = (((wib >> 3) << 3) + (tok >> 3) + shift) & 63;
                int w = (((wib & 7) << 3) + (tok & 7) + shift) & 63;
                orow = (size_t)bb * 4096 + h * 64 + w;
            } else {
                orow = (size_t)row;
            }
            #pragma unroll
            for (int cf = 0; cf < 4; ++cf) {
                const int colb = bn * 64 + cf * 16 + g * 4;
                const f32x4 bv = *(const f32x4*)(bias + colb);
                if (EPI == 0) {
                    u16x4 o;
                    #pragma unroll
                    for (int e = 0; e < 4; ++e) o[e] = f2b(acc[cf][rf][e] + bv[e]);
                    *(u16x4*)((u16*)out + (size_t)row * N + colb) = o;
                } else if (EPI == 1) {
                    u16x4 o;
                    #pragma unroll
                    for (int e = 0; e < 4; ++e) o[e] = f2b(fast_gelu(acc[cf][rf][e] + bv[e]));
                    *(u16x4*)((u16*)out + (size_t)row * N + colb) = o;
                } else {
                    float rv[4];
                    if (RBF16) {
                        const u16x4 rb = *(const u16x4*)((const u16*)resid + orow * N + colb);
                        #pragma unroll
                        for (int e = 0; e < 4; ++e) rv[e] = b2f(rb[e]);
                    } else {
                        const f32x4 rb = *(const f32x4*)((const float*)resid + orow * N + colb);
                        #pragma unroll
                        for (int e = 0; e < 4; ++e) rv[e] = rb[e];
                    }
                    u16x4 o;
                    #pragma unroll
                    for (int e = 0; e < 4; ++e) o[e] = f2b(rv[e] + acc[cf][rf][e] + bv[e]);
                    *(u16x4*)((u16*)out + orow * N + colb) = o;
                }
            }
        }
        FENCE();
        __builtin_amdgcn_s_barrier();
        FENCE();
    }
#undef STAGE
}

// ======== general-K 128x128 GEMM (MLP2): 4-buf, depth-2, 1 barrier/iter ====
template<int OUTBF16>
__global__ __launch_bounds__(256)
void gemm_k4(const u16* __restrict__ A, const u16* __restrict__ Bt,
             const float* __restrict__ bias, void* __restrict__ out,
             const u16* __restrict__ resid, int M, int N, int K)
{
    __shared__ u16 As[4][128][32];
    __shared__ u16 Bs[4][128][32];
    const int tid = threadIdx.x, lane = tid & 63, wv = tid >> 6;
    const int g = lane >> 4, r = lane & 15;
    const int wr = wv >> 1, wc = wv & 1;
    const int nwg = gridDim.x * gridDim.y;
    const int lid = blockIdx.y * gridDim.x + blockIdx.x;
    const int qq = nwg >> 3, r8 = nwg & 7;
    const int xcd = lid & 7, pos = lid >> 3;
    const int nid = (xcd < r8 ? xcd * (qq + 1) : r8 * (qq + 1) + (xcd - r8) * qq) + pos;
    const int bm = nid / gridDim.x, bn = nid % gridDim.x;
    f32x4 acc[4][4] = {};
    const int arow = wv * 16 + (lane >> 2);
    const int scol = (((lane & 3) ^ ((lane >> 2) & 3) ^ ((lane >> 4) & 1)) * 8);
    const u16* gA = A + (size_t)(bm * 128 + arow) * K + scol;
    const u16* gB = Bt + (size_t)(bn * 128 + arow) * K + scol;
    const int nk = K >> 5;
    const int rc = (g ^ (r & 3) ^ ((r >> 2) & 1)) * 8;

#define STAGE(t) do { \
        u16* a_ = &As[(t) & 3][0][0]; u16* b_ = &Bs[(t) & 3][0][0]; \
        GLOAD_LDS16(gA + (size_t)(t) * 32,                    a_ + wv * 512); \
        GLOAD_LDS16(gA + (size_t)(t) * 32 + (size_t)64 * K,   a_ + 2048 + wv * 512); \
        GLOAD_LDS16(gB + (size_t)(t) * 32,                    b_ + wv * 512); \
        GLOAD_LDS16(gB + (size_t)(t) * 32 + (size_t)64 * K,   b_ + 2048 + wv * 512); \
    } while (0)

    STAGE(0);
    STAGE(1);
    for (int kt = 0; kt < nk; ++kt) {
        const int cur = kt & 3;
        if (kt + 2 < nk) {
            STAGE(kt + 2);
            asm volatile("s_waitcnt vmcnt(8)" ::: "memory");
        } else if (kt + 1 < nk) {
            asm volatile("s_waitcnt vmcnt(4)" ::: "memory");
        } else {
            asm volatile("s_waitcnt vmcnt(0)" ::: "memory");
        }
        __builtin_amdgcn_s_barrier();
        FENCE();
        bf16x8 af[4], bf[4];
        #pragma unroll
        for (int i = 0; i < 4; ++i)
            af[i] = *(const bf16x8*)(&As[cur][wr * 64 + i * 16 + r][rc]);
        #pragma unroll
        for (int j = 0; j < 4; ++j)
            bf[j] = *(const bf16x8*)(&Bs[cur][wc * 64 + j * 16 + r][rc]);
        __builtin_amdgcn_s_setprio(1);
        #pragma unroll
        for (int j = 0; j < 4; ++j)
            #pragma unroll
            for (int i = 0; i < 4; ++i)
                acc[j][i] = __builtin_amdgcn_mfma_f32_16x16x32_bf16(bf[j], af[i], acc[j][i], 0, 0, 0);
        __builtin_amdgcn_s_setprio(0);
        asm volatile("s_waitcnt lgkmcnt(0)" ::: "memory");
        __builtin_amdgcn_sched_barrier(0);
    }
#undef STAGE

    #pragma unroll
    for (int i = 0; i < 4; ++i) {
        const int row = bm * 128 + wr * 64 + i * 16 + r;
        #pragma unroll
        for (int j = 0; j < 4; ++j) {
            const int colb = bn * 128 + wc * 64 + j * 16 + g * 4;
            const f32x4 bv = *(const f32x4*)(bias + colb);
            const u16x4 rb = *(const u16x4*)(resid + (size_t)row * N + colb);
            if (OUTBF16) {
                u16x4 o;
                #pragma unroll
                for (int e = 0; e < 4; ++e) o[e] = f2b(b2f(rb[e]) + acc[j][i][e] + bv[e]);
                *(u16x4*)((u16*)out + (size_t)row * N + colb) = o;
            } else {
                f32x4 o;
                #pragma unroll
                for (int e = 0; e < 4; ++e) o[e] = b2f(rb[e]) + acc[j][i][e] + bv[e];
                *(f32x4*)((float*)out + (size_t)row * N + colb) = o;
            }
        }
    }
}

// ---------------- MFMA attention: one block per window, wave = 2 heads -----
template<int SHIFTED>
__global__ __launch_bounds__(256)
void attn_mfma(const u16* __restrict__ qkv, const float* __restrict__ bmT,
               u16* __restrict__ out)
{
    __shared__ u16 pbuf[4][64 * 72];
    __shared__ u16 vbuf[4][32 * 72];
    const int tid = threadIdx.x, lane = tid & 63, wv = tid >> 6;
    const int g = lane >> 4, r = lane & 15;
    const int win = blockIdx.x;
    u16* P  = pbuf[wv];
    u16* Vt = vbuf[wv];
    const u16* base = qkv + (size_t)win * 64 * 768;
    int cls = 0;
    if (SHIFTED) {
        int wib = win & 63;
        cls = (((wib >> 3) == 7) ? 2 : 0) + (((wib & 7) == 7) ? 1 : 0);
    }
    const float sc = 0.17677669529663687f * 1.4426950408889634f;

    for (int hh = 0; hh < 2; ++hh) {
        const int h = wv * 2 + hh;
        const float* bmh = bmT + ((size_t)cls * 8 + h) * 4096;
        bf16x8 kf[4], qf[4];
        #pragma unroll
        for (int i = 0; i < 4; ++i) {
            kf[i] = *(const bf16x8*)(base + (size_t)(i * 16 + r) * 768 + 256 + h * 32 + g * 8);
            qf[i] = *(const bf16x8*)(base + (size_t)(i * 16 + r) * 768 +       h * 32 + g * 8);
        }
        #pragma unroll
        for (int d0 = 0; d0 < 32; d0 += 8) {
            u16x8 vv = *(const u16x8*)(base + (size_t)lane * 768 + 512 + h * 32 + d0);
            #pragma unroll
            for (int e = 0; e < 8; ++e) Vt[(d0 + e) * 72 + lane] = vv[e];
        }
        f32x4 acc[4][4] = {};
        #pragma unroll
        for (int i = 0; i < 4; ++i)
            #pragma unroll
            for (int j = 0; j < 4; ++j)
                acc[i][j] = __builtin_amdgcn_mfma_f32_16x16x32_bf16(kf[i], qf[j], acc[i][j], 0, 0, 0);
        #pragma unroll
        for (int i = 0; i < 4; ++i) {
            const int kb = (i * 16 + g * 4) * 64;
            #pragma unroll
            for (int j = 0; j < 4; ++j) {
                const int qq = j * 16 + r;
                #pragma unroll
                for (int rr = 0; rr < 4; ++rr)
                    acc[i][j][rr] = acc[i][j][rr] * sc + bmh[kb + rr * 64 + qq];
            }
        }
        float inv_[4];
        #pragma unroll
        for (int j = 0; j < 4; ++j) {
            float m = acc[0][j][0];
            #pragma unroll
            for (int i = 0; i < 4; ++i)
                #pragma unroll
                for (int rr = 0; rr < 4; ++rr) m = fmaxf(m, acc[i][j][rr]);
            m = fmaxf(m, __shfl_xor(m, 16));
            m = fmaxf(m, __shfl_xor(m, 32));
            float s = 0.f;
            #pragma unroll
            for (int i = 0; i < 4; ++i)
                #pragma unroll
                for (int rr = 0; rr < 4; ++rr) {
                    float p = exp2f(acc[i][j][rr] - m);
                    acc[i][j][rr] = p; s += p;
                }
            s += __shfl_xor(s, 16);
            s += __shfl_xor(s, 32);
            inv_[j] = 1.f / s;
        }
        #pragma unroll
        for (int j = 0; j < 4; ++j) {
            const float iv = inv_[j];
            #pragma unroll
            for (int i = 0; i < 4; ++i) {
                u16x4 w;
                #pragma unroll
                for (int rr = 0; rr < 4; ++rr) w[rr] = f2b(acc[i][j][rr] * iv);
                *(u16x4*)(P + (j * 16 + r) * 72 + i * 16 + g * 4) = w;
            }
        }
        f32x4 o[2][4] = {};
        #pragma unroll
        for (int ks = 0; ks < 2; ++ks) {
            bf16x8 pa[4], vb[2];
            #pragma unroll
            for (int i = 0; i < 4; ++i)
                pa[i] = *(const bf16x8*)(P + (i * 16 + r) * 72 + ks * 32 + g * 8);
            #pragma unroll
            for (int j = 0; j < 2; ++j)
                vb[j] = *(const bf16x8*)(Vt + (j * 16 + r) * 72 + ks * 32 + g * 8);
            #pragma unroll
            for (int j = 0; j < 2; ++j)
                #pragma unroll
                for (int i = 0; i < 4; ++i)
                    o[j][i] = __builtin_amdgcn_mfma_f32_16x16x32_bf16(vb[j], pa[i], o[j][i], 0, 0, 0);
        }
        u16* op = out + (size_t)win * 64 * 256 + h * 32;
        #pragma unroll
        for (int i = 0; i < 4; ++i) {
            const int qrow = i * 16 + r;
            #pragma unroll
            for (int j = 0; j < 2; ++j) {
                u16x4 w;
                #pragma unroll
                for (int rr = 0; rr < 4; ++rr) w[rr] = f2b(o[j][i][rr]);
                *(u16x4*)(op + (size_t)qrow * 256 + j * 16 + g * 4) = w;
            }
        }
    }
}

// ---------------------------------------------------------------------------
extern "C" void kernel_launch(void* const* d_in, const int* in_sizes, int n_in,
                              void* d_out, int out_size, void* d_ws, size_t ws_size,
                              hipStream_t stream)
{
    (void)in_sizes; (void)n_in; (void)out_size; (void)ws_size;
    const float* x = (const float*)d_in[0];
    char* ws = (char*)d_ws;
    size_t off = 0;
    auto alloc = [&](size_t bytes) { void* p = ws + off; off += (bytes + 255) & ~(size_t)255; return p; };

    u16 *wtq[2], *wto[2], *wt1[2], *wt2[2];
    float* bmT[2];
    for (int i = 0; i < 2; ++i) {
        wtq[i] = (u16*)alloc((size_t)768 * 256 * 2);
        wto[i] = (u16*)alloc((size_t)256 * 256 * 2);
        wt1[i] = (u16*)alloc((size_t)1024 * 256 * 2);
        wt2[i] = (u16*)alloc((size_t)256 * 1024 * 2);
        bmT[i] = (float*)alloc((size_t)4 * 8 * 64 * 64 * 4);
    }
    u16*  xw  = (u16*)alloc((size_t)65536 * 256 * 2);    // LN out / attn out
    u16*  big = (u16*)alloc((size_t)65536 * 1024 * 2);   // qkv / mlp hidden
    u16*  x1b = (u16*)alloc((size_t)65536 * 256 * 2);    // residual stream (bf16)
    u16*  xob = (u16*)alloc((size_t)65536 * 256 * 2);    // block0 output (bf16)
    float* outp = (float*)d_out;

    for (int blk = 0; blk < 2; ++blk) {
        const float* const* P = (const float* const*)(d_in + 1 + blk * 15);
        transpose_w<<<dim3(768 / 32, 256 / 32), 256, 0, stream>>>(P[2], wtq[blk], 256, 768);
        transpose_w<<<dim3(256 / 32, 256 / 32), 256, 0, stream>>>(P[5], wto[blk], 256, 256);
        transpose_w<<<dim3(1024 / 32, 256 / 32), 256, 0, stream>>>(P[11], wt1[blk], 256, 1024);
        transpose_w<<<dim3(256 / 32, 1024 / 32), 256, 0, stream>>>(P[13], wt2[blk], 1024, 256);
        build_bias<<<512, 256, 0, stream>>>(P[4], bmT[blk]);
    }

    // ---- block 0 (resid source: x f32; block output -> xob bf16)
    {
        const float* const* P = (const float* const*)(d_in + 1);
        ln_win_kernel<0><<<16384, 256, 0, stream>>>(x, P[0], P[1], xw, 0);
        areg_gemm<0, 0><<<512, 256, 0, stream>>>(xw, wtq[0], P[3], big, nullptr, 768, 0);
        attn_mfma<0><<<1024, 256, 0, stream>>>(big, bmT[0], xw);
        areg_gemm<2, 0><<<512, 256, 0, stream>>>(xw, wto[0], P[6], x1b, x, 256, 0);
        ln2_kernel<<<16384, 256, 0, stream>>>(x1b, P[7], P[8], P[9], P[10], xw);
        areg_gemm<1, 0><<<512, 256, 0, stream>>>(xw, wt1[0], P[12], big, nullptr, 1024, 0);
        gemm_k4<1><<<dim3(2, 512), 256, 0, stream>>>(big, wt2[0], P[14], xob, x1b, 65536, 256, 1024);
    }
    // ---- block 1 (resid source: xob bf16; final output -> d_out f32)
    {
        const float* const* P = (const float* const*)(d_in + 1 + 15);
        ln_win_kernel<1><<<16384, 256, 0, stream>>>(xob, P[0], P[1], xw, 4);
        areg_gemm<0, 0><<<512, 256, 0, stream>>>(xw, wtq[1], P[3], big, nullptr, 768, 0);
        attn_mfma<1><<<1024, 256, 0, stream>>>(big, bmT[1], xw);
        areg_gemm<2, 1><<<512, 256, 0, stream>>>(xw, wto[1], P[6], x1b, xob, 256, 4);
        ln2_kernel<<<16384, 256, 0, stream>>>(x1b, P[7], P[8], P[9], P[10], xw);
        areg_gemm<1, 0><<<512, 256, 0, stream>>>(xw, wt1[1], P[12], big, nullptr, 1024, 0);
        gemm_k4<0><<<dim3(2, 512), 256, 0, stream>>>(big, wt2[1], P[14], outp, x1b, 65536, 256, 1024);
    }
}